// Round 2
// baseline (134.287 us; speedup 1.0000x reference)
//
#include <hip/hip_runtime.h>

#define B_ 4
#define L_ 2048
#define E_ 512
#define H_ 8
#define NROW (B_*L_)        // 8192 flat rows
#define SZ (NROW*E_)        // 4194304
#define NH (B_*H_)          // 32 batch-heads

typedef unsigned short u16;
typedef unsigned int u32;
typedef __attribute__((ext_vector_type(8))) __bf16 bf16x8;
typedef __attribute__((ext_vector_type(8))) u16 u16x8;
typedef __attribute__((ext_vector_type(4))) float f32x4;

__device__ __forceinline__ u16 f2bf(float f) {
  union { float f; u32 u; } v; v.f = f;
  u32 r = v.u + 0x7FFFu + ((v.u >> 16) & 1u);   // RNE
  return (u16)(r >> 16);
}
__device__ __forceinline__ float bf2f(u16 s) {
  union { u32 u; float f; } v; v.u = ((u32)s) << 16;
  return v.f;
}
// async global->LDS, 16B per lane. lds dest = wave-uniform base + lane*16.
__device__ __forceinline__ void async16(const u16* g, u16* l) {
  __builtin_amdgcn_global_load_lds(
      (const __attribute__((address_space(1))) u32*)g,
      (__attribute__((address_space(3))) u32*)l, 16, 0, 0);
}

// ---------- fused fp32->bf16 converts ----------
// blocks [0,2048): X ; [2048,2560): 4 weights (128 blocks each)
__global__ __launch_bounds__(256) void cvt_all(const float* __restrict__ X,
    const float* __restrict__ W0, const float* __restrict__ W1,
    const float* __restrict__ W2, const float* __restrict__ W3,
    u16* __restrict__ Y, u16* __restrict__ Y0, u16* __restrict__ Y1,
    u16* __restrict__ Y2, u16* __restrict__ Y3) {
  const int bid = blockIdx.x;
  const float* src;
  u16* dst;
  int off;
  if (bid < 2048) { src = X; dst = Y; off = bid * 2048; }
  else {
    const int t = bid - 2048, s = t >> 7, r = t & 127;
    src = (s == 0) ? W0 : (s == 1) ? W1 : (s == 2) ? W2 : W3;
    dst = (s == 0) ? Y0 : (s == 1) ? Y1 : (s == 2) ? Y2 : Y3;
    off = r * 2048;
  }
  const int i0 = off + threadIdx.x * 8;
  f32x4 a = *(const f32x4*)(src + i0);
  f32x4 b = *(const f32x4*)(src + i0 + 4);
  u16x8 o;
#pragma unroll
  for (int j = 0; j < 4; ++j) { o[j] = f2bf(a[j]); o[4 + j] = f2bf(b[j]); }
  *(u16x8*)(dst + i0) = o;
}

// ---------- QKV MFMA GEMM: m97 geometry. 128x128 tile, BK=64, grid (64,4,3) ----------
// 4 waves 2x2, each 64x64 -> 32 MFMA per barrier pair. 3 blocks/CU pinned.
// Wave cols bn+wn..+64 = exactly one head slice -> softmax stays wave-local.
// z=0: Q (+softmax64), z=1: K (+softmax64), z=2: V (plain bf16)
// softmax: no max-subtraction needed — |X@W| small; exp() safe in f32.
__global__ __launch_bounds__(256, 3) void qkv_gemm(const u16* __restrict__ X,
    const u16* __restrict__ Wq, const u16* __restrict__ Wk, const u16* __restrict__ Wv,
    const float* __restrict__ bq, const float* __restrict__ bk, const float* __restrict__ bv,
    u16* __restrict__ Qo, u16* __restrict__ Ko, u16* __restrict__ Vo) {
  __shared__ __align__(16) union {
    struct { u16 a[2][128 * 32]; u16 b[2][128 * 32]; } st;  // 32 KB staging
    u16 ep[4][16 * 72];                                     // per-wave epilogue stage
  } sh;
  const int z = blockIdx.z;
  const u16* W = (z == 0) ? Wq : (z == 1) ? Wk : Wv;
  const float* bias = (z == 0) ? bq : (z == 1) ? bk : bv;
  u16* C = (z == 0) ? Qo : (z == 1) ? Ko : Vo;
  const int tid = threadIdx.x;
  const int w = tid >> 6, lane = tid & 63;
  const int bm = blockIdx.x * 128, bn = blockIdx.y * 128;
  const int wm = (w >> 1) * 64, wn = (w & 1) * 64;
  const int fr = lane & 15, quad = lane >> 4;
  const int c0 = tid, c1 = tid + 256;      // chunk ids within a 128x32 panel
  const int ar0 = c0 >> 2, ak0 = (c0 & 3) * 8;
  const int ar1 = c1 >> 2, ak1 = (c1 & 3) * 8;
  f32x4 acc[4][4] = {};
  for (int k0 = 0; k0 < E_; k0 += 64) {
    __syncthreads();
#pragma unroll
    for (int p = 0; p < 2; ++p) {
      const int kp = k0 + p * 32;
      async16(X + (size_t)(bm + ar0) * E_ + kp + ak0, sh.st.a[p] + c0 * 8);
      async16(X + (size_t)(bm + ar1) * E_ + kp + ak1, sh.st.a[p] + c1 * 8);
      async16(W + (size_t)(bn + ar0) * E_ + kp + ak0, sh.st.b[p] + c0 * 8);
      async16(W + (size_t)(bn + ar1) * E_ + kp + ak1, sh.st.b[p] + c1 * 8);
    }
    __syncthreads();
#pragma unroll
    for (int p = 0; p < 2; ++p) {
      bf16x8 af[4], bf[4];
#pragma unroll
      for (int t = 0; t < 4; ++t) {
        af[t] = *(const bf16x8*)(sh.st.a[p] + (wm + t * 16 + fr) * 32 + quad * 8);
        bf[t] = *(const bf16x8*)(sh.st.b[p] + (wn + t * 16 + fr) * 32 + quad * 8);
      }
#pragma unroll
      for (int i = 0; i < 4; ++i)
#pragma unroll
        for (int j = 0; j < 4; ++j)
          acc[i][j] = __builtin_amdgcn_mfma_f32_16x16x32_bf16(af[i], bf[j], acc[i][j], 0, 0, 0);
    }
  }
  __syncthreads();   // all fragment reads done before LDS reuse
  u16* ep = sh.ep[w];
#pragma unroll
  for (int i = 0; i < 4; ++i) {   // 16-row slab of the wave's 64x64 tile
    if (z < 2) {
#pragma unroll
      for (int r = 0; r < 4; ++r) {
        float v[4];
#pragma unroll
        for (int nt = 0; nt < 4; ++nt)
          v[nt] = acc[i][nt][r] + bias[bn + wn + nt * 16 + fr];
        float e[4], ssum = 0.f;
#pragma unroll
        for (int nt = 0; nt < 4; ++nt) { e[nt] = __expf(v[nt]); ssum += e[nt]; }
#pragma unroll
        for (int off = 1; off < 16; off <<= 1) ssum += __shfl_xor(ssum, off, 64);
        const float inv = 1.f / ssum;
#pragma unroll
        for (int nt = 0; nt < 4; ++nt)
          ep[(quad * 4 + r) * 72 + nt * 16 + fr] = f2bf(e[nt] * inv);
      }
    } else {
#pragma unroll
      for (int r = 0; r < 4; ++r)
#pragma unroll
        for (int nt = 0; nt < 4; ++nt)
          ep[(quad * 4 + r) * 72 + nt * 16 + fr] =
              f2bf(acc[i][nt][r] + bias[bn + wn + nt * 16 + fr]);
    }
    // coalesced store: 16 rows x 64 cols bf16
#pragma unroll
    for (int pass = 0; pass < 2; ++pass) {
      const int row = pass * 8 + (lane >> 3), ch = lane & 7;
      u16x8 val = *(const u16x8*)(ep + row * 72 + ch * 8);
      *(u16x8*)(C + (size_t)(bm + wm + i * 16 + row) * E_ + bn + wn + ch * 8) = val;
    }
  }
}

// ---------- kv_reduce stage 1 (MFMA): grid (NH, 16), 1 wave/block ----------
// SWAPPED operands vs r1: A = K rows (d), B = V rows (e) -> Mt' is d-major:
// Part[(n*16+sy)*4096 + d*64 + e] = partial sum_l K[l][d]*V[l][e].
// Row sums via ones-fragments: mfma(K^T,1) rows = Ksum[d], mfma(1,V^T) cols = Vsum[e].
__global__ __launch_bounds__(64) void kv_part(const u16* __restrict__ K,
    const u16* __restrict__ V, float* __restrict__ Part,
    float* __restrict__ KPart, float* __restrict__ VPart) {
  __shared__ __align__(16) u16 sT[2][2][64 * 40];   // [buf][K/V][e or d][l..40]
  const int n = blockIdx.x, b = n >> 3, h = n & 7;
  const int sy = blockIdx.y;
  const int lane = threadIdx.x;
  const int lr = lane >> 1, half = lane & 1;        // staging: row l, 32-col half
  const int fr = lane & 15, quad = lane >> 4;       // mfma fragment coords
  const int e0 = half * 32;
  f32x4 acc[4][4] = {};
  f32x4 accK[4] = {};
  f32x4 accV[4] = {};
  union { u16x8 u; bf16x8 b; } one;
#pragma unroll
  for (int j = 0; j < 8; ++j) one.u[j] = 0x3F80;    // bf16 1.0
  u16x8 rK[4], rV[4], nK[4], nV[4];
  {
    const u16* gK = K + (size_t)((sy * 128 + lr) * B_ + b) * E_ + h * 64 + e0;
    const u16* gV = V + (size_t)((sy * 128 + lr) * B_ + b) * E_ + h * 64 + e0;
#pragma unroll
    for (int q = 0; q < 4; ++q) {
      rK[q] = *(const u16x8*)(gK + q * 8);
      rV[q] = *(const u16x8*)(gV + q * 8);
    }
  }
#pragma unroll
  for (int c = 0; c < 4; ++c) {
    const int buf = c & 1;
    u16* dK = &sT[buf][0][0];
    u16* dV = &sT[buf][1][0];
    // transpose-scatter this chunk: [l][e] regs -> [e][l] LDS
#pragma unroll
    for (int q = 0; q < 4; ++q)
#pragma unroll
      for (int j = 0; j < 8; ++j) {
        const int e = e0 + q * 8 + j;
        dK[e * 40 + lr] = rK[q][j];
        dV[e * 40 + lr] = rV[q][j];
      }
    // prefetch next chunk's global loads under this chunk's compute
    if (c < 3) {
      const u16* gK = K + (size_t)((sy * 128 + (c + 1) * 32 + lr) * B_ + b) * E_ + h * 64 + e0;
      const u16* gV = V + (size_t)((sy * 128 + (c + 1) * 32 + lr) * B_ + b) * E_ + h * 64 + e0;
#pragma unroll
      for (int q = 0; q < 4; ++q) {
        nK[q] = *(const u16x8*)(gK + q * 8);
        nV[q] = *(const u16x8*)(gV + q * 8);
      }
    }
    bf16x8 af[4], bf[4];
#pragma unroll
    for (int t = 0; t < 4; ++t) {
      af[t] = *(const bf16x8*)(dK + (t * 16 + fr) * 40 + quad * 8);   // A row = d
      bf[t] = *(const bf16x8*)(dV + (t * 16 + fr) * 40 + quad * 8);   // B row = e
    }
#pragma unroll
    for (int i = 0; i < 4; ++i)
#pragma unroll
      for (int j = 0; j < 4; ++j)
        acc[i][j] = __builtin_amdgcn_mfma_f32_16x16x32_bf16(af[i], bf[j], acc[i][j], 0, 0, 0);
#pragma unroll
    for (int i = 0; i < 4; ++i)
      accK[i] = __builtin_amdgcn_mfma_f32_16x16x32_bf16(af[i], one.b, accK[i], 0, 0, 0);
#pragma unroll
    for (int j = 0; j < 4; ++j)
      accV[j] = __builtin_amdgcn_mfma_f32_16x16x32_bf16(one.b, bf[j], accV[j], 0, 0, 0);
#pragma unroll
    for (int q = 0; q < 4; ++q) { rK[q] = nK[q]; rV[q] = nV[q]; }
  }
  // C/D layout: col = lane&15, row = quad*4 + reg. acc[i][j] -> (d=i*16+quad*4+r, e=j*16+fr)
  float* Pp = Part + (size_t)(n * 16 + sy) * 4096;
#pragma unroll
  for (int i = 0; i < 4; ++i)
#pragma unroll
    for (int j = 0; j < 4; ++j)
#pragma unroll
      for (int r = 0; r < 4; ++r)
        Pp[(i * 16 + quad * 4 + r) * 64 + j * 16 + fr] = acc[i][j][r];
  if (fr == 0) {
#pragma unroll
    for (int i = 0; i < 4; ++i)
#pragma unroll
      for (int r = 0; r < 4; ++r)
        KPart[(n * 16 + sy) * 64 + i * 16 + quad * 4 + r] = accK[i][r];  // all cols identical
  }
  if (quad == 0) {
#pragma unroll
    for (int j = 0; j < 4; ++j)
      VPart[(n * 16 + sy) * 64 + j * 16 + fr] = accV[j][0];   // all rows identical
  }
}

// ---------- kv_reduce stage 2: sum 16 slice-partials; Mt bf16 + Ksum also bf16 ----------
// blocks [0,512): Mtbf (32*4096 outputs); [512,528): Ksum/Vsum (4096 outputs)
__global__ __launch_bounds__(256) void kv_merge(const float* __restrict__ Part,
    const float* __restrict__ KPart, const float* __restrict__ VPart,
    u16* __restrict__ Mtbf, float* __restrict__ Ks, float* __restrict__ Vs,
    u16* __restrict__ Ksb) {
  const int bid = blockIdx.x, tid = threadIdx.x;
  if (bid < 512) {
    const int oi = bid * 256 + tid;            // 0..131071
    const int n = oi >> 12, j = oi & 4095;
    const float* p = Part + (size_t)n * 16 * 4096 + j;
    float s = 0.f;
#pragma unroll
    for (int sl = 0; sl < 16; ++sl) s += p[sl * 4096];
    Mtbf[oi] = f2bf(s);
  } else {
    const int i = (bid - 512) * 256 + tid;     // 0..4095
    const int which = i >> 11, rem = i & 2047;
    const int n = rem >> 6, d = rem & 63;
    const float* p = (which ? VPart : KPart) + (n * 16) * 64 + d;
    float s = 0.f;
#pragma unroll
    for (int sl = 0; sl < 16; ++sl) s += p[sl * 64];
    if (which) Vs[n * 64 + d] = s;
    else { Ks[n * 64 + d] = s; Ksb[n * 64 + d] = f2bf(s); }  // n*64+d == b*512+dg
  }
}

// ---------- gemm_G: Gt[b][f][dg] = 2 * sum_e Mt'[n][d][e] * Wo[f][h*64+e] ----------
// grid (NH), 256 thr, 4 waves x 128 f-rows. K=64 (2 k-steps). No LDS staging:
// Mtbf (8 KB) and Wo fragments read direct from global (L2-resident).
// Also Upart[n][f] = 62 * sum_e Vs[n*64+e] * Wo[f][h*64+e].
__global__ __launch_bounds__(256) void gemm_G(const u16* __restrict__ Mtbf,
    const u16* __restrict__ Wo, const float* __restrict__ Vs,
    u16* __restrict__ Gt, float* __restrict__ Upart) {
  __shared__ __align__(16) u16 ep[4][16 * 72];
  const int n = blockIdx.x, b = n >> 3, h = n & 7;
  const int tid = threadIdx.x, w = tid >> 6, lane = tid & 63;
  const int fr = lane & 15, quad = lane >> 4;
  const u16* Mn = Mtbf + (size_t)n * 4096;
  f32x4 acc[8][4] = {};
#pragma unroll
  for (int ks = 0; ks < 2; ++ks) {
    bf16x8 bfr[4];
#pragma unroll
    for (int j = 0; j < 4; ++j)
      bfr[j] = *(const bf16x8*)(Mn + (j * 16 + fr) * 64 + ks * 32 + quad * 8);
#pragma unroll
    for (int i = 0; i < 8; ++i) {
      bf16x8 afr = *(const bf16x8*)(Wo + (size_t)(w * 128 + i * 16 + fr) * E_ +
                                    h * 64 + ks * 32 + quad * 8);
#pragma unroll
      for (int j = 0; j < 4; ++j)
        acc[i][j] = __builtin_amdgcn_mfma_f32_16x16x32_bf16(afr, bfr[j], acc[i][j], 0, 0, 0);
    }
  }
  // Upart: f = tid, tid+256
#pragma unroll
  for (int t = 0; t < 2; ++t) {
    const int f = t * 256 + tid;
    const u16* wr = Wo + (size_t)f * E_ + h * 64;
    float s = 0.f;
#pragma unroll
    for (int c = 0; c < 8; ++c) {
      u16x8 v = *(const u16x8*)(wr + c * 8);
#pragma unroll
      for (int j = 0; j < 8; ++j) s = fmaf(bf2f(v[j]), Vs[n * 64 + c * 8 + j], s);
    }
    Upart[(size_t)n * 512 + f] = 62.f * s;
  }
  // store Gt via per-wave LDS slab (coalesced u16x8)
  u16* e0 = ep[w];
#pragma unroll
  for (int i = 0; i < 8; ++i) {
#pragma unroll
    for (int j = 0; j < 4; ++j)
#pragma unroll
      for (int r = 0; r < 4; ++r)
        e0[(quad * 4 + r) * 72 + j * 16 + fr] = f2bf(2.f * acc[i][j][r]);
#pragma unroll
    for (int pass = 0; pass < 2; ++pass) {
      const int row = pass * 8 + (lane >> 3), ch = lane & 7;
      u16x8 val = *(const u16x8*)(e0 + row * 72 + ch * 8);
      *(u16x8*)(Gt + (size_t)(b * 512 + w * 128 + i * 16 + row) * E_ + h * 64 + ch * 8) = val;
    }
  }
}

// ---------- final GEMM: out[l,b,f] = (Q@Gt^T + U_b)/den + bo ----------
// grid (16 l-tiles, 8 f-tiles, 4 batches), 128x64 tile, BK=64 (2x32 panels).
// den[row] = 2*Q_row.Ksvec + 62L computed via one extra MFMA per panel against a
// Ks-broadcast B fragment (all 16 B-rows equal Ks) -> den lands per-lane aligned
// with acc rows, no cross-lane reduce.
__global__ __launch_bounds__(256) void final_gemm(const u16* __restrict__ Q,
    const u16* __restrict__ Gt, const u16* __restrict__ Ksb,
    const float* __restrict__ Upart, const float* __restrict__ bo,
    float* __restrict__ C) {
  __shared__ __align__(16) union {
    struct { u16 a[2][128 * 32]; u16 b[2][64 * 32]; } st;  // 24 KB
    float ep[4][16 * 68];                                  // per-wave fp32 stage
  } sh;
  __shared__ __align__(16) u16 sKsb[512];
  __shared__ float sU[64], sBo[64];
  const int tid = threadIdx.x;
  const int w = tid >> 6, lane = tid & 63;
  const int bz = blockIdx.z;
  const int l0 = blockIdx.x * 128, bn = blockIdx.y * 64;
  const int fr = lane & 15, quad = lane >> 4;
  const int c0 = tid, c1 = tid + 256;
  const int ar0 = c0 >> 2, ak0 = (c0 & 3) * 8;
  const int ar1 = c1 >> 2, ak1 = (c1 & 3) * 8;
  const u16* Gb = Gt + (size_t)(bz * 512 + bn) * E_;
  if (tid < 64) {
    float s = 0.f;
#pragma unroll
    for (int hh = 0; hh < 8; ++hh) s += Upart[(size_t)(bz * 8 + hh) * 512 + bn + tid];
    sU[tid] = s;
    sBo[tid] = bo[bn + tid];
  } else if (tid < 128) {
    *(u16x8*)(sKsb + (tid - 64) * 8) = *(const u16x8*)(Ksb + bz * 512 + (tid - 64) * 8);
  }
  f32x4 acc[2][4] = {};
  f32x4 accD[2] = {};
  for (int k0 = 0; k0 < E_; k0 += 64) {
    __syncthreads();
#pragma unroll
    for (int p = 0; p < 2; ++p) {
      const int kp = k0 + p * 32;
      async16(Q + (size_t)((l0 + ar0) * B_ + bz) * E_ + kp + ak0, sh.st.a[p] + c0 * 8);
      async16(Q + (size_t)((l0 + ar1) * B_ + bz) * E_ + kp + ak1, sh.st.a[p] + c1 * 8);
      async16(Gb + (size_t)ar0 * E_ + kp + ak0, sh.st.b[p] + c0 * 8);
    }
    __syncthreads();
#pragma unroll
    for (int p = 0; p < 2; ++p) {
      bf16x8 af[2], bf[4];
#pragma unroll
      for (int mt = 0; mt < 2; ++mt)
        af[mt] = *(const bf16x8*)(sh.st.a[p] + (w * 32 + mt * 16 + fr) * 32 + quad * 8);
#pragma unroll
      for (int nt = 0; nt < 4; ++nt)
        bf[nt] = *(const bf16x8*)(sh.st.b[p] + (nt * 16 + fr) * 32 + quad * 8);
      const bf16x8 bfK = *(const bf16x8*)(sKsb + k0 + p * 32 + quad * 8);  // fr-uniform
#pragma unroll
      for (int mt = 0; mt < 2; ++mt) {
#pragma unroll
        for (int nt = 0; nt < 4; ++nt)
          acc[mt][nt] = __builtin_amdgcn_mfma_f32_16x16x32_bf16(af[mt], bf[nt],
                                                                acc[mt][nt], 0, 0, 0);
        accD[mt] = __builtin_amdgcn_mfma_f32_16x16x32_bf16(af[mt], bfK, accD[mt], 0, 0, 0);
      }
    }
  }
  __syncthreads();
  float* ep = sh.ep[w];
#pragma unroll
  for (int mt = 0; mt < 2; ++mt) {
#pragma unroll
    for (int r = 0; r < 4; ++r) {
      const float den = fmaxf(2.f * accD[mt][r] + 62.f * (float)L_, 1e-6f);
      const float invd = 1.f / den;
#pragma unroll
      for (int nt = 0; nt < 4; ++nt)
        ep[(quad * 4 + r) * 68 + nt * 16 + fr] =
            (acc[mt][nt][r] + sU[nt * 16 + fr]) * invd + sBo[nt * 16 + fr];
    }
#pragma unroll
    for (int p = 0; p < 4; ++p) {
      const int id = p * 64 + lane;
      const int row = id >> 4, ch = id & 15;
      f32x4 val = *(const f32x4*)(ep + row * 68 + ch * 4);
      *(f32x4*)(C + (size_t)((l0 + w * 32 + mt * 16 + row) * B_ + bz) * E_ + bn + ch * 4) = val;
    }
  }
}

extern "C" void kernel_launch(void* const* d_in, const int* in_sizes, int n_in,
                              void* d_out, int out_size, void* d_ws, size_t ws_size,
                              hipStream_t stream) {
  const float* query = (const float*)d_in[0];
  const float* Wq = (const float*)d_in[1];
  const float* bq = (const float*)d_in[2];
  const float* Wk = (const float*)d_in[3];
  const float* bk = (const float*)d_in[4];
  const float* Wv = (const float*)d_in[5];
  const float* bv = (const float*)d_in[6];
  const float* Wo = (const float*)d_in[7];
  const float* bo = (const float*)d_in[8];
  float* out = (float*)d_out;

  char* ws = (char*)d_ws;
  u16* Xbf  = (u16*)(ws);                        // 8 MB; dead after qkv_gemm
  u16* Qbf  = (u16*)(ws + 8388608);
  u16* Kbf  = (u16*)(ws + 16777216);
  u16* Vbf  = (u16*)(ws + 25165824);
  u16* Wqb  = (u16*)(ws + 41943040);             // 512 KB each
  u16* Wkb  = (u16*)(ws + 42467328);
  u16* Wvb  = (u16*)(ws + 42991616);
  u16* Wob  = (u16*)(ws + 43515904);
  u16* Mtbf = (u16*)(ws + 44040192);             // 256 KB (NH*4096 bf16)
  float* Ks = (float*)(ws + 44564480);           // 8 KB
  float* Vs = (float*)(ws + 44572672);           // 8 KB
  float* KPart = (float*)(ws + 44580864);        // 128 KB (512*64 f32)
  float* VPart = (float*)(ws + 44711936);        // 128 KB
  u16* Gtb   = (u16*)(ws + 44843008);            // 2 MB (4*512*512 bf16)
  float* Upart = (float*)(ws + 46940160);        // 64 KB (32*512 f32)
  u16* Ksb   = (u16*)(ws + 47005696);            // 4 KB (2048 bf16)
  float* Part  = (float*)Xbf;                    // alias: 512*4096 f32 = 8 MB exactly

  cvt_all<<<2560, 256, 0, stream>>>(query, Wq, Wk, Wv, Wo,
                                    Xbf, Wqb, Wkb, Wvb, Wob);
  qkv_gemm<<<dim3(NROW / 128, E_ / 128, 3), 256, 0, stream>>>(
      Xbf, Wqb, Wkb, Wvb, bq, bk, bv, Qbf, Kbf, Vbf);
  kv_part<<<dim3(NH, 16), 64, 0, stream>>>(Kbf, Vbf, Part, KPart, VPart);
  kv_merge<<<528, 256, 0, stream>>>(Part, KPart, VPart, Mtbf, Ks, Vs, Ksb);
  gemm_G<<<NH, 256, 0, stream>>>(Mtbf, Wob, Vs, Gtb, Upart);
  final_gemm<<<dim3(L_ / 128, E_ / 64, B_), 256, 0, stream>>>(
      Qbf, Gtb, Ksb, Upart, bo, out);
}

// Round 3
// 128.956 us; speedup vs baseline: 1.0413x; 1.0413x over previous
//
#include <hip/hip_runtime.h>

#define B_ 4
#define L_ 2048
#define E_ 512
#define H_ 8
#define NROW (B_*L_)        // 8192 flat rows
#define SZ (NROW*E_)        // 4194304
#define NH (B_*H_)          // 32 batch-heads

typedef unsigned short u16;
typedef unsigned int u32;
typedef __attribute__((ext_vector_type(8))) __bf16 bf16x8;
typedef __attribute__((ext_vector_type(8))) u16 u16x8;
typedef __attribute__((ext_vector_type(4))) float f32x4;

__device__ __forceinline__ u16 f2bf(float f) {
  union { float f; u32 u; } v; v.f = f;
  u32 r = v.u + 0x7FFFu + ((v.u >> 16) & 1u);   // RNE
  return (u16)(r >> 16);
}
__device__ __forceinline__ float bf2f(u16 s) {
  union { u32 u; float f; } v; v.u = ((u32)s) << 16;
  return v.f;
}
// async global->LDS, 16B per lane. lds dest = wave-uniform base + lane*16.
__device__ __forceinline__ void async16(const u16* g, u16* l) {
  __builtin_amdgcn_global_load_lds(
      (const __attribute__((address_space(1))) u32*)g,
      (__attribute__((address_space(3))) u32*)l, 16, 0, 0);
}

// ---------- fused fp32->bf16 converts ----------
// blocks [0,2048): X ; [2048,2560): 4 weights (128 blocks each)
__global__ __launch_bounds__(256) void cvt_all(const float* __restrict__ X,
    const float* __restrict__ W0, const float* __restrict__ W1,
    const float* __restrict__ W2, const float* __restrict__ W3,
    u16* __restrict__ Y, u16* __restrict__ Y0, u16* __restrict__ Y1,
    u16* __restrict__ Y2, u16* __restrict__ Y3) {
  const int bid = blockIdx.x;
  const float* src;
  u16* dst;
  int off;
  if (bid < 2048) { src = X; dst = Y; off = bid * 2048; }
  else {
    const int t = bid - 2048, s = t >> 7, r = t & 127;
    src = (s == 0) ? W0 : (s == 1) ? W1 : (s == 2) ? W2 : W3;
    dst = (s == 0) ? Y0 : (s == 1) ? Y1 : (s == 2) ? Y2 : Y3;
    off = r * 2048;
  }
  const int i0 = off + threadIdx.x * 8;
  f32x4 a = *(const f32x4*)(src + i0);
  f32x4 b = *(const f32x4*)(src + i0 + 4);
  u16x8 o;
#pragma unroll
  for (int j = 0; j < 4; ++j) { o[j] = f2bf(a[j]); o[4 + j] = f2bf(b[j]); }
  *(u16x8*)(dst + i0) = o;
}

// ---------- QKV MFMA GEMM: m97 geometry. 128x128 tile, BK=64, grid (64,4,3) ----------
// 4 waves 2x2, each 64x64 -> 32 MFMA per barrier pair. 3 blocks/CU pinned.
// Wave cols bn+wn..+64 = exactly one head slice -> softmax stays wave-local.
// z=0: Q (+softmax64), z=1: K (+softmax64), z=2: V (plain bf16)
// softmax: no max-subtraction needed — |X@W| small; exp() safe in f32.
__global__ __launch_bounds__(256, 3) void qkv_gemm(const u16* __restrict__ X,
    const u16* __restrict__ Wq, const u16* __restrict__ Wk, const u16* __restrict__ Wv,
    const float* __restrict__ bq, const float* __restrict__ bk, const float* __restrict__ bv,
    u16* __restrict__ Qo, u16* __restrict__ Ko, u16* __restrict__ Vo) {
  __shared__ __align__(16) union {
    struct { u16 a[2][128 * 32]; u16 b[2][128 * 32]; } st;  // 32 KB staging
    u16 ep[4][16 * 72];                                     // per-wave epilogue stage
  } sh;
  const int z = blockIdx.z;
  const u16* W = (z == 0) ? Wq : (z == 1) ? Wk : Wv;
  const float* bias = (z == 0) ? bq : (z == 1) ? bk : bv;
  u16* C = (z == 0) ? Qo : (z == 1) ? Ko : Vo;
  const int tid = threadIdx.x;
  const int w = tid >> 6, lane = tid & 63;
  const int bm = blockIdx.x * 128, bn = blockIdx.y * 128;
  const int wm = (w >> 1) * 64, wn = (w & 1) * 64;
  const int fr = lane & 15, quad = lane >> 4;
  const int c0 = tid, c1 = tid + 256;      // chunk ids within a 128x32 panel
  const int ar0 = c0 >> 2, ak0 = (c0 & 3) * 8;
  const int ar1 = c1 >> 2, ak1 = (c1 & 3) * 8;
  f32x4 acc[4][4] = {};
  for (int k0 = 0; k0 < E_; k0 += 64) {
    __syncthreads();
#pragma unroll
    for (int p = 0; p < 2; ++p) {
      const int kp = k0 + p * 32;
      async16(X + (size_t)(bm + ar0) * E_ + kp + ak0, sh.st.a[p] + c0 * 8);
      async16(X + (size_t)(bm + ar1) * E_ + kp + ak1, sh.st.a[p] + c1 * 8);
      async16(W + (size_t)(bn + ar0) * E_ + kp + ak0, sh.st.b[p] + c0 * 8);
      async16(W + (size_t)(bn + ar1) * E_ + kp + ak1, sh.st.b[p] + c1 * 8);
    }
    __syncthreads();
#pragma unroll
    for (int p = 0; p < 2; ++p) {
      bf16x8 af[4], bf[4];
#pragma unroll
      for (int t = 0; t < 4; ++t) {
        af[t] = *(const bf16x8*)(sh.st.a[p] + (wm + t * 16 + fr) * 32 + quad * 8);
        bf[t] = *(const bf16x8*)(sh.st.b[p] + (wn + t * 16 + fr) * 32 + quad * 8);
      }
#pragma unroll
      for (int i = 0; i < 4; ++i)
#pragma unroll
        for (int j = 0; j < 4; ++j)
          acc[i][j] = __builtin_amdgcn_mfma_f32_16x16x32_bf16(af[i], bf[j], acc[i][j], 0, 0, 0);
    }
  }
  __syncthreads();   // all fragment reads done before LDS reuse
  u16* ep = sh.ep[w];
#pragma unroll
  for (int i = 0; i < 4; ++i) {   // 16-row slab of the wave's 64x64 tile
    if (z < 2) {
#pragma unroll
      for (int r = 0; r < 4; ++r) {
        float v[4];
#pragma unroll
        for (int nt = 0; nt < 4; ++nt)
          v[nt] = acc[i][nt][r] + bias[bn + wn + nt * 16 + fr];
        float e[4], ssum = 0.f;
#pragma unroll
        for (int nt = 0; nt < 4; ++nt) { e[nt] = __expf(v[nt]); ssum += e[nt]; }
#pragma unroll
        for (int off = 1; off < 16; off <<= 1) ssum += __shfl_xor(ssum, off, 64);
        const float inv = 1.f / ssum;
#pragma unroll
        for (int nt = 0; nt < 4; ++nt)
          ep[(quad * 4 + r) * 72 + nt * 16 + fr] = f2bf(e[nt] * inv);
      }
    } else {
#pragma unroll
      for (int r = 0; r < 4; ++r)
#pragma unroll
        for (int nt = 0; nt < 4; ++nt)
          ep[(quad * 4 + r) * 72 + nt * 16 + fr] =
              f2bf(acc[i][nt][r] + bias[bn + wn + nt * 16 + fr]);
    }
    // coalesced store: 16 rows x 64 cols bf16
#pragma unroll
    for (int pass = 0; pass < 2; ++pass) {
      const int row = pass * 8 + (lane >> 3), ch = lane & 7;
      u16x8 val = *(const u16x8*)(ep + row * 72 + ch * 8);
      *(u16x8*)(C + (size_t)(bm + wm + i * 16 + row) * E_ + bn + wn + ch * 8) = val;
    }
  }
}

// ---------- out-projection GEMM: 128x64 tile, two BK=32 panels, fp32 out, grid (64,8) ----------
__global__ __launch_bounds__(256) void gemm_out(const u16* __restrict__ X,
    const u16* __restrict__ W, const float* __restrict__ bias, float* __restrict__ C) {
  __shared__ __align__(16) union {
    struct { u16 a[2][128 * 32]; u16 b[2][64 * 32]; } st;  // 24 KB
    float ep[4][16 * 68];                                  // per-wave fp32 stage
  } sh;
  const int tid = threadIdx.x;
  const int w = tid >> 6, lane = tid & 63;
  const int bm = blockIdx.x * 128, bn = blockIdx.y * 64;
  const int fr = lane & 15, quad = lane >> 4;
  const int c0 = tid, c1 = tid + 256;
  const int ar0 = c0 >> 2, ak0 = (c0 & 3) * 8;
  const int ar1 = c1 >> 2, ak1 = (c1 & 3) * 8;
  f32x4 acc[2][4] = {};
  for (int k0 = 0; k0 < E_; k0 += 64) {
    __syncthreads();
#pragma unroll
    for (int p = 0; p < 2; ++p) {
      const int kp = k0 + p * 32;
      async16(X + (size_t)(bm + ar0) * E_ + kp + ak0, sh.st.a[p] + c0 * 8);
      async16(X + (size_t)(bm + ar1) * E_ + kp + ak1, sh.st.a[p] + c1 * 8);
      async16(W + (size_t)(bn + ar0) * E_ + kp + ak0, sh.st.b[p] + c0 * 8);
    }
    __syncthreads();
#pragma unroll
    for (int p = 0; p < 2; ++p) {
      bf16x8 af[2], bf[4];
#pragma unroll
      for (int mt = 0; mt < 2; ++mt)
        af[mt] = *(const bf16x8*)(sh.st.a[p] + (w * 32 + mt * 16 + fr) * 32 + quad * 8);
#pragma unroll
      for (int nt = 0; nt < 4; ++nt)
        bf[nt] = *(const bf16x8*)(sh.st.b[p] + (nt * 16 + fr) * 32 + quad * 8);
#pragma unroll
      for (int mt = 0; mt < 2; ++mt)
#pragma unroll
        for (int nt = 0; nt < 4; ++nt)
          acc[mt][nt] = __builtin_amdgcn_mfma_f32_16x16x32_bf16(af[mt], bf[nt],
                                                                acc[mt][nt], 0, 0, 0);
    }
  }
  __syncthreads();
  float* ep = sh.ep[w];
#pragma unroll
  for (int mt = 0; mt < 2; ++mt) {
#pragma unroll
    for (int r = 0; r < 4; ++r)
#pragma unroll
      for (int nt = 0; nt < 4; ++nt)
        ep[(quad * 4 + r) * 68 + nt * 16 + fr] = acc[mt][nt][r] + bias[bn + nt * 16 + fr];
#pragma unroll
    for (int p = 0; p < 4; ++p) {
      const int id = p * 64 + lane;
      const int row = id >> 4, ch = id & 15;
      f32x4 val = *(const f32x4*)(ep + row * 68 + ch * 4);
      *(f32x4*)(C + (size_t)(bm + w * 32 + mt * 16 + row) * E_ + bn + ch * 4) = val;
    }
  }
}

// ---------- kv_reduce stage 1 (MFMA, 4-wave): grid (NH, 4), 256 thr ----------
// Wave w handles rows sy*512 + w*128 .. +128 in 4 chunks of 32 (private LDS
// staging region, no barriers inside the loop). Then one cross-wave LDS reduce
// into wave 0, which writes Part slice (n*4+sy):
// Part[(n*4+sy)*4096 + e*64 + d] = partial sum_l K[l][d]*V[l][e]
// Row sums via ones-fragments: mfma(1,K^T) -> Ksum[d], mfma(V^T,1) -> Vsum[e].
__global__ __launch_bounds__(256) void kv_part(const u16* __restrict__ K,
    const u16* __restrict__ V, float* __restrict__ Part,
    float* __restrict__ KPart, float* __restrict__ VPart) {
  __shared__ __align__(16) union {
    u16 stg[4][2][2][64 * 40];        // [wave][buf][K/V][e or d][l..40] = 80 KB
    float red[3][64][100];            // 76.8 KB cross-wave reduce (after barrier)
  } sh;
  const int n = blockIdx.x, b = n >> 3, h = n & 7;
  const int sy = blockIdx.y;
  const int tid = threadIdx.x, w = tid >> 6, lane = tid & 63;
  const int lr = lane >> 1, half = lane & 1;        // staging: row l, 32-col half
  const int fr = lane & 15, quad = lane >> 4;       // mfma fragment coords
  const int e0 = half * 32;
  const int row0 = sy * 512 + w * 128;
  f32x4 acc[4][4] = {};
  f32x4 accK[4] = {};
  f32x4 accV[4] = {};
  union { u16x8 u; bf16x8 b; } one;
#pragma unroll
  for (int j = 0; j < 8; ++j) one.u[j] = 0x3F80;    // bf16 1.0
  u16x8 rK[4], rV[4], nK[4], nV[4];
  {
    const u16* gK = K + (size_t)((row0 + lr) * B_ + b) * E_ + h * 64 + e0;
    const u16* gV = V + (size_t)((row0 + lr) * B_ + b) * E_ + h * 64 + e0;
#pragma unroll
    for (int q = 0; q < 4; ++q) {
      rK[q] = *(const u16x8*)(gK + q * 8);
      rV[q] = *(const u16x8*)(gV + q * 8);
    }
  }
#pragma unroll
  for (int c = 0; c < 4; ++c) {
    const int buf = c & 1;
    u16* dK = &sh.stg[w][buf][0][0];
    u16* dV = &sh.stg[w][buf][1][0];
    // transpose-scatter this chunk: [l][e] regs -> [e][l] LDS
#pragma unroll
    for (int q = 0; q < 4; ++q)
#pragma unroll
      for (int j = 0; j < 8; ++j) {
        const int e = e0 + q * 8 + j;
        dK[e * 40 + lr] = rK[q][j];
        dV[e * 40 + lr] = rV[q][j];
      }
    // prefetch next chunk's global loads under this chunk's compute
    if (c < 3) {
      const u16* gK = K + (size_t)((row0 + (c + 1) * 32 + lr) * B_ + b) * E_ + h * 64 + e0;
      const u16* gV = V + (size_t)((row0 + (c + 1) * 32 + lr) * B_ + b) * E_ + h * 64 + e0;
#pragma unroll
      for (int q = 0; q < 4; ++q) {
        nK[q] = *(const u16x8*)(gK + q * 8);
        nV[q] = *(const u16x8*)(gV + q * 8);
      }
    }
    bf16x8 af[4], bf[4];
#pragma unroll
    for (int t = 0; t < 4; ++t) {
      af[t] = *(const bf16x8*)(dV + (t * 16 + fr) * 40 + quad * 8);   // A row = e
      bf[t] = *(const bf16x8*)(dK + (t * 16 + fr) * 40 + quad * 8);   // B row = d
    }
#pragma unroll
    for (int i = 0; i < 4; ++i)
#pragma unroll
      for (int j = 0; j < 4; ++j)
        acc[i][j] = __builtin_amdgcn_mfma_f32_16x16x32_bf16(af[i], bf[j], acc[i][j], 0, 0, 0);
#pragma unroll
    for (int j = 0; j < 4; ++j)
      accK[j] = __builtin_amdgcn_mfma_f32_16x16x32_bf16(one.b, bf[j], accK[j], 0, 0, 0);
#pragma unroll
    for (int i = 0; i < 4; ++i)
      accV[i] = __builtin_amdgcn_mfma_f32_16x16x32_bf16(af[i], one.b, accV[i], 0, 0, 0);
#pragma unroll
    for (int q = 0; q < 4; ++q) { rK[q] = nK[q]; rV[q] = nV[q]; }
  }
  __syncthreads();                 // all waves done with staging LDS
  if (w > 0) {
    float* rp = &sh.red[w - 1][lane][0];
#pragma unroll
    for (int t = 0; t < 16; ++t) *(f32x4*)(rp + t * 4) = acc[t >> 2][t & 3];
#pragma unroll
    for (int t = 0; t < 4; ++t) *(f32x4*)(rp + 64 + t * 4) = accK[t];
#pragma unroll
    for (int t = 0; t < 4; ++t) *(f32x4*)(rp + 80 + t * 4) = accV[t];
  }
  __syncthreads();
  if (w == 0) {
#pragma unroll
    for (int p = 0; p < 3; ++p) {
      const float* rp = &sh.red[p][lane][0];
#pragma unroll
      for (int t = 0; t < 16; ++t) acc[t >> 2][t & 3] += *(const f32x4*)(rp + t * 4);
#pragma unroll
      for (int t = 0; t < 4; ++t) accK[t] += *(const f32x4*)(rp + 64 + t * 4);
#pragma unroll
      for (int t = 0; t < 4; ++t) accV[t] += *(const f32x4*)(rp + 80 + t * 4);
    }
    // C/D layout: col = lane&15, row = quad*4 + reg. acc[i][j] -> (e=i*16+quad*4+r, d=j*16+fr)
    float* Pp = Part + (size_t)(n * 4 + sy) * 4096;
#pragma unroll
    for (int i = 0; i < 4; ++i)
#pragma unroll
      for (int j = 0; j < 4; ++j)
#pragma unroll
        for (int r = 0; r < 4; ++r)
          Pp[(i * 16 + quad * 4 + r) * 64 + j * 16 + fr] = acc[i][j][r];
    if (quad == 0) {
#pragma unroll
      for (int j = 0; j < 4; ++j)
        KPart[(n * 4 + sy) * 64 + j * 16 + fr] = accK[j][0];   // all rows identical
    }
    if (fr == 0) {
#pragma unroll
      for (int i = 0; i < 4; ++i)
#pragma unroll
        for (int r = 0; r < 4; ++r)
          VPart[(n * 4 + sy) * 64 + i * 16 + quad * 4 + r] = accV[i][r];  // all cols identical
    }
  }
}

// ---------- apply: A = (2*Q@M + 62*Vsum) / den, den = 2*q.Ksum + 62*L ----------
// grid (NH, 16). kv_merge FUSED into the prologue: while async Q staging is in
// flight, each thread sums the 4 L2-hot Part slices -> bf16 sM, and the first
// 128 threads sum KPart/VPart -> sKs/sVs.
__global__ __launch_bounds__(256) void apply_mfma(const u16* __restrict__ Qbf,
    const float* __restrict__ Part, const float* __restrict__ KPart,
    const float* __restrict__ VPart, u16* __restrict__ Abf) {
  __shared__ __align__(16) u16 sQ[128 * 64];
  __shared__ __align__(16) u16 sM[64 * 64];
  __shared__ float sKs[64], sVs[64], sDen[128];
  const int n = blockIdx.x, b = n >> 3, h = n & 7;
  const int l0 = blockIdx.y * 128;
  const int tid = threadIdx.x, w = tid >> 6, lane = tid & 63;
  const int fr = lane & 15, quad = lane >> 4;
#pragma unroll
  for (int j = 0; j < 4; ++j) {
    const int rloc = w * 32 + j * 8;
    const int row = rloc + (lane >> 3);
    const int k = (lane & 7) * 8;
    async16(Qbf + (size_t)((l0 + row) * B_ + b) * E_ + h * 64 + k, sQ + rloc * 64);
  }
  // fused kv_merge: sM[e][d] = bf16( sum_{s<4} Part[(n*4+s)*4096 + e*64 + d] )
  {
    const int e = tid >> 2, d0 = (tid & 3) * 16;
    const float* Pp = Part + (size_t)n * 4 * 4096 + e * 64 + d0;
    f32x4 s0 = {}, s1 = {}, s2 = {}, s3 = {};
#pragma unroll
    for (int s = 0; s < 4; ++s) {
      const float* q = Pp + s * 4096;
      s0 += *(const f32x4*)(q);
      s1 += *(const f32x4*)(q + 4);
      s2 += *(const f32x4*)(q + 8);
      s3 += *(const f32x4*)(q + 12);
    }
    u16x8 o0, o1;
#pragma unroll
    for (int j = 0; j < 4; ++j) {
      o0[j] = f2bf(s0[j]); o0[4 + j] = f2bf(s1[j]);
      o1[j] = f2bf(s2[j]); o1[4 + j] = f2bf(s3[j]);
    }
    *(u16x8*)(sM + e * 64 + d0) = o0;
    *(u16x8*)(sM + e * 64 + d0 + 8) = o1;
  }
  if (tid < 64) {
    float s = 0.f;
#pragma unroll
    for (int sl = 0; sl < 4; ++sl) s += KPart[(n * 4 + sl) * 64 + tid];
    sKs[tid] = s;
  } else if (tid < 128) {
    float s = 0.f;
#pragma unroll
    for (int sl = 0; sl < 4; ++sl) s += VPart[(n * 4 + sl) * 64 + tid - 64];
    sVs[tid - 64] = s;
  }
  __syncthreads();
  union { u16x8 u; bf16x8 bv; } aU[2][2];
  bf16x8 bF[4][2];
#pragma unroll
  for (int mt = 0; mt < 2; ++mt)
#pragma unroll
    for (int ks = 0; ks < 2; ++ks)
      aU[mt][ks].u = *(const u16x8*)(sQ + (w * 32 + mt * 16 + fr) * 64 + ks * 32 + quad * 8);
#pragma unroll
  for (int nt = 0; nt < 4; ++nt)
#pragma unroll
    for (int ks = 0; ks < 2; ++ks)
      bF[nt][ks] = *(const bf16x8*)(sM + (nt * 16 + fr) * 64 + ks * 32 + quad * 8);
  float pden[2] = {0.f, 0.f};
#pragma unroll
  for (int mt = 0; mt < 2; ++mt)
#pragma unroll
    for (int ks = 0; ks < 2; ++ks)
#pragma unroll
      for (int j = 0; j < 8; ++j)
        pden[mt] = fmaf(bf2f(aU[mt][ks].u[j]), sKs[ks * 32 + quad * 8 + j], pden[mt]);
#pragma unroll
  for (int mt = 0; mt < 2; ++mt) {
    pden[mt] += __shfl_xor(pden[mt], 16, 64);
    pden[mt] += __shfl_xor(pden[mt], 32, 64);
    if (quad == 0)
      sDen[w * 32 + mt * 16 + fr] = fmaxf(2.f * pden[mt] + 62.f * (float)L_, 1e-6f);
  }
  __syncthreads();
  f32x4 acc[2][4];
#pragma unroll
  for (int mt = 0; mt < 2; ++mt)
#pragma unroll
    for (int nt = 0; nt < 4; ++nt) {
      const float iv = 31.f * sVs[nt * 16 + fr];
      acc[mt][nt] = (f32x4){iv, iv, iv, iv};
#pragma unroll
      for (int ks = 0; ks < 2; ++ks)
        acc[mt][nt] = __builtin_amdgcn_mfma_f32_16x16x32_bf16(aU[mt][ks].bv, bF[nt][ks],
                                                              acc[mt][nt], 0, 0, 0);
    }
#pragma unroll
  for (int mt = 0; mt < 2; ++mt)
#pragma unroll
    for (int r = 0; r < 4; ++r) {
      const int rloc = w * 32 + mt * 16 + quad * 4 + r;
      const float invd = 2.f / sDen[rloc];
      const size_t orow = (size_t)((l0 + rloc) * B_ + b) * E_ + h * 64;
#pragma unroll
      for (int nt = 0; nt < 4; ++nt)
        Abf[orow + nt * 16 + fr] = f2bf(acc[mt][nt][r] * invd);
    }
}

extern "C" void kernel_launch(void* const* d_in, const int* in_sizes, int n_in,
                              void* d_out, int out_size, void* d_ws, size_t ws_size,
                              hipStream_t stream) {
  const float* query = (const float*)d_in[0];
  const float* Wq = (const float*)d_in[1];
  const float* bq = (const float*)d_in[2];
  const float* Wk = (const float*)d_in[3];
  const float* bk = (const float*)d_in[4];
  const float* Wv = (const float*)d_in[5];
  const float* bv = (const float*)d_in[6];
  const float* Wo = (const float*)d_in[7];
  const float* bo = (const float*)d_in[8];
  float* out = (float*)d_out;

  char* ws = (char*)d_ws;
  u16* Xbf  = (u16*)(ws);                        // 8 MB; dead after qkv_gemm
  u16* Qbf  = (u16*)(ws + 8388608);
  u16* Kbf  = (u16*)(ws + 16777216);
  u16* Vbf  = (u16*)(ws + 25165824);
  u16* Abf  = (u16*)(ws + 33554432);
  u16* Wqb  = (u16*)(ws + 41943040);             // 512 KB each
  u16* Wkb  = (u16*)(ws + 42467328);
  u16* Wvb  = (u16*)(ws + 42991616);
  u16* Wob  = (u16*)(ws + 43515904);
  float* KPart = (float*)(ws + 44580864);        // 32 KB (128*64 f32)
  float* VPart = (float*)(ws + 44711936);        // 32 KB
  float* Part  = (float*)Xbf;                    // alias: 128*4096 f32 = 2 MB

  cvt_all<<<2560, 256, 0, stream>>>(query, Wq, Wk, Wv, Wo,
                                    Xbf, Wqb, Wkb, Wvb, Wob);
  qkv_gemm<<<dim3(NROW / 128, E_ / 128, 3), 256, 0, stream>>>(
      Xbf, Wqb, Wkb, Wvb, bq, bk, bv, Qbf, Kbf, Vbf);
  kv_part<<<dim3(NH, 4), 256, 0, stream>>>(Kbf, Vbf, Part, KPart, VPart);
  apply_mfma<<<dim3(NH, L_ / 128), 256, 0, stream>>>(Qbf, Part, KPart, VPart, Abf);
  gemm_out<<<dim3(NROW / 128, E_ / 64), 256, 0, stream>>>(Abf, Wob, bo, out);
}